// Round 4
// baseline (780.136 us; speedup 1.0000x reference)
//
#include <hip/hip_runtime.h>
#include <cstdint>
#include <cstddef>

#define B_    2048
#define L_    13
#define H_    768
#define NROW  (B_ * L_)          // 26624 flattened hidden rows
#define RTEMP 20.0f              // 1 / 0.05
#define NT    24                 // K tiles: 768 / 32
#define RS    1536               // global row stride bytes (H_ * 2)

typedef short bf16x8 __attribute__((ext_vector_type(8)));
typedef float f32x4  __attribute__((ext_vector_type(4)));

static __device__ __forceinline__ unsigned short f2bf(float f) {
  union { float f; unsigned int i; } v; v.f = f;
  unsigned int r = v.i + 0x7fffu + ((v.i >> 16) & 1u);   // RNE
  return (unsigned short)(r >> 16);
}
static __device__ __forceinline__ unsigned int pack2(float a, float b) {
  return ((unsigned int)f2bf(b) << 16) | (unsigned int)f2bf(a);
}

__device__ __forceinline__ void llds16(const void* g, void* l) {
  __builtin_amdgcn_global_load_lds(
      (const __attribute__((address_space(1))) void*)g,
      (__attribute__((address_space(3))) void*)l, 16, 0, 0);
}

#define BAR do { asm volatile("" ::: "memory");            \
    __builtin_amdgcn_s_barrier();                          \
    asm volatile("" ::: "memory"); } while (0)
#define WAIT_LGKM do { asm volatile("s_waitcnt lgkmcnt(0)" ::: "memory"); \
    __builtin_amdgcn_sched_barrier(0); } while (0)

// ---------------------------------------------------------------------------
// Kernel 1: L2-normalize rows, cast to bf16. One wave per row, 4 rows/block.
// ---------------------------------------------------------------------------
__global__ __launch_bounds__(256) void k_normalize(
    const float* __restrict__ cls, const float* __restrict__ hidden,
    unsigned short* __restrict__ cn, unsigned short* __restrict__ hn)
{
  const int wid = threadIdx.x >> 6, lane = threadIdx.x & 63;
  const int row = blockIdx.x * 4 + wid;
  const float4* src; unsigned short* dst;
  if (row < B_) { src = (const float4*)(cls + (size_t)row * H_);          dst = cn + (size_t)row * H_; }
  else          { src = (const float4*)(hidden + (size_t)(row - B_) * H_); dst = hn + (size_t)(row - B_) * H_; }

  float4 x0 = src[lane], x1 = src[lane + 64], x2 = src[lane + 128];
  float ss = x0.x*x0.x + x0.y*x0.y + x0.z*x0.z + x0.w*x0.w
           + x1.x*x1.x + x1.y*x1.y + x1.z*x1.z + x1.w*x1.w
           + x2.x*x2.x + x2.y*x2.y + x2.z*x2.z + x2.w*x2.w;
#pragma unroll
  for (int m = 1; m < 64; m <<= 1) ss += __shfl_xor(ss, m);
  const float sc = 1.0f / fmaxf(sqrtf(ss), 1e-8f);

  uint2* d2 = (uint2*)dst;
  uint2 p;
  p.x = pack2(x0.x * sc, x0.y * sc); p.y = pack2(x0.z * sc, x0.w * sc); d2[lane]       = p;
  p.x = pack2(x1.x * sc, x1.y * sc); p.y = pack2(x1.z * sc, x1.w * sc); d2[lane + 64]  = p;
  p.x = pack2(x2.x * sc, x2.y * sc); p.y = pack2(x2.z * sc, x2.w * sc); d2[lane + 128] = p;
}

// ---------------------------------------------------------------------------
// Kernel 2: 256x256 tile, BK=32, 8 waves (2M x 4N), wave tile 128x64
// (62%-MfmaUtil LDS-BW-cap geometry). 2-slot LDS double-buffer (2 x 32KB =
// 64KB -> 2 blocks/CU), ONE barrier per K-tile, stage issued at tile top
// (distance-1; loads get ~600cy of ds_read+MFMA to land, L2-hot B via
// per-XCD M-inner mapping). Paired-row XOR swizzle (R2/R3-validated, 0
// conflicts). Fused exp/mask/row-sum epilogue.
// ---------------------------------------------------------------------------
__global__ __launch_bounds__(512, 4) void k_gemm(
    const unsigned short* __restrict__ cn,
    const unsigned short* __restrict__ hn,
    float* __restrict__ S_all,
    float* __restrict__ alignedD)
{
  __shared__ __align__(16) char lds[65536];   // 2 slots x (A 16KB | B 16KB)

  const int tid  = threadIdx.x;
  const int lane = tid & 63;
  const int wid  = tid >> 6;           // 0..7
  const int wm   = wid >> 2;           // 0..1  (M half: 128 rows)
  const int wn   = wid & 3;            // 0..3  (N quarter: 64 cols)
  const int fr   = lane & 15, q = lane >> 4, fr2 = (lane & 15) >> 1;

  // 832 blocks = 8 XCD x (13 N-panels x 8 M-panels), M-inner: B-panel
  // (393KB) L2-hot across its 8 M-blocks; cn (3.1MB) L2-resident per XCD.
  const int wg   = blockIdx.x;
  const int idx  = wg >> 3;
  const int brow = (idx & 7) * 256;
  const int bcol = ((wg & 7) * 13 + (idx >> 3)) * 256;

  // --- staging map (linear LDS dest, inverse-swizzled global source) ------
  const int slot_un = (tid & 7) ^ ((tid >> 3) & 7);
  const int srow = 2 * (tid >> 3) + (slot_un >> 2);   // 0..127
  const int scb  = (slot_un & 3) << 4;
  const char* gA = (const char*)cn + (size_t)(brow + srow) * RS + scb;
  const char* gB = (const char*)hn + (size_t)(bcol + srow) * RS + scb;
  char* ldst = lds + tid * 16;

#define STAGE_A(slot, t) do { char* d_ = ldst + (slot) * 32768;           \
    llds16(gA + (t) * 64,            d_);                                 \
    llds16(gA + (t) * 64 + 128 * RS, d_ + 8192); } while (0)
#define STAGE_B(slot, t) do { char* d_ = ldst + (slot) * 32768 + 16384;   \
    llds16(gB + (t) * 64,            d_);                                 \
    llds16(gB + (t) * 64 + 128 * RS, d_ + 8192); } while (0)

  // --- fragment read offsets (paired-row XOR swizzle) ---------------------
  const int swz  = ((((fr & 1) << 2) | q) ^ (fr2 & 7)) << 4;
  const int offA = (wm * 64 + fr2) * 128 + swz;            // + m*1024
  const int offB = 16384 + (wn * 32 + fr2) * 128 + swz;    // + n*1024

  f32x4 acc[8][4] = {};

  // prologue: K-tile 0 staged
  STAGE_A(0, 0); STAGE_B(0, 0);
  asm volatile("s_waitcnt vmcnt(0)" ::: "memory");
  BAR;

  for (int t = 0; t < NT; ++t) {
    const char* bb = lds + (t & 1) * 32768;

    // stage next tile FIRST (max issue->wait gap; WAR safe: slot (t+1)&1
    // was last read in tile t-1, completed behind the barrier)
    if (t + 1 < NT) { STAGE_A((t + 1) & 1, t + 1); STAGE_B((t + 1) & 1, t + 1); }

    bf16x8 a0[4], a1[4], bf[4];
#pragma unroll
    for (int i = 0; i < 4; ++i) a0[i] = *(const bf16x8*)(bb + offA + i * 1024);
#pragma unroll
    for (int i = 0; i < 4; ++i) a1[i] = *(const bf16x8*)(bb + offA + 4096 + i * 1024);
#pragma unroll
    for (int i = 0; i < 4; ++i) bf[i] = *(const bf16x8*)(bb + offB + i * 1024);
    WAIT_LGKM;

    __builtin_amdgcn_s_setprio(1);
#pragma unroll
    for (int mi = 0; mi < 4; ++mi)
#pragma unroll
      for (int ni = 0; ni < 4; ++ni)
        acc[mi][ni] = __builtin_amdgcn_mfma_f32_16x16x32_bf16(
            a0[mi], bf[ni], acc[mi][ni], 0, 0, 0);
#pragma unroll
    for (int mi = 0; mi < 4; ++mi)
#pragma unroll
      for (int ni = 0; ni < 4; ++ni)
        acc[mi + 4][ni] = __builtin_amdgcn_mfma_f32_16x16x32_bf16(
            a1[mi], bf[ni], acc[mi + 4][ni], 0, 0, 0);
    __builtin_amdgcn_s_setprio(0);

    // next tile's 4 loads are the only ones in flight; they've had the
    // whole ds_read+MFMA span to land -> near-free wait
    asm volatile("s_waitcnt vmcnt(0)" ::: "memory");
    BAR;
  }
#undef STAGE_A
#undef STAGE_B

  // --- epilogue: row = brow+wm*128+m*16+q*4+j, col = bcol+wn*64+n*16+fr ---
  const int rowb = brow + wm * 128;
  const int colb = bcol + wn * 64;
#pragma unroll
  for (int mi = 0; mi < 8; ++mi) {
#pragma unroll
    for (int j = 0; j < 4; ++j) {
      const int grow = rowb + mi * 16 + q * 4 + j;
      float v = 0.f;
#pragma unroll
      for (int ni = 0; ni < 4; ++ni) {
        const int gcol = colb + ni * 16 + fr;
        const float a = acc[mi][ni][j];
        if ((unsigned)(gcol - grow * 13) < 13u) alignedD[gcol] = a;  // raw dot
        v += ((gcol & 2047) == grow) ? 0.f : __expf(RTEMP * a);     // masked sum
      }
      v += __shfl_xor(v, 1); v += __shfl_xor(v, 2);
      v += __shfl_xor(v, 4); v += __shfl_xor(v, 8);
      if (fr == 0) atomicAdd(&S_all[grow], v);
    }
  }
}

// ---------------------------------------------------------------------------
// Kernel 3: per row i: loss_i = sum_l [ log(exp(20 d_l) + s_i) - 20 d_l ].
// ---------------------------------------------------------------------------
__global__ __launch_bounds__(256) void k_finalize(
    const float* __restrict__ S_all, const float* __restrict__ alignedD,
    float* __restrict__ out)
{
  const int i = blockIdx.x * 256 + threadIdx.x;
  const int lane = threadIdx.x & 63, wid = threadIdx.x >> 6;
  const float s = S_all[i];
  float accv = 0.f;
#pragma unroll
  for (int l = 0; l < L_; l++) {
    const float d = RTEMP * alignedD[i * L_ + l];
    accv += logf(__expf(d) + s) - d;
  }
#pragma unroll
  for (int m = 1; m < 64; m <<= 1) accv += __shfl_xor(accv, m);
  __shared__ float wsum[4];
  if (lane == 0) wsum[wid] = accv;
  __syncthreads();
  if (threadIdx.x == 0)
    atomicAdd(out, (wsum[0] + wsum[1] + wsum[2] + wsum[3]) * (1.0f / (float)(B_ * L_)));
}

// ---------------------------------------------------------------------------
extern "C" void kernel_launch(void* const* d_in, const int* in_sizes, int n_in,
                              void* d_out, int out_size, void* d_ws, size_t ws_size,
                              hipStream_t stream) {
  const float* cls    = (const float*)d_in[0];
  const float* hidden = (const float*)d_in[1];
  float* out = (float*)d_out;

  // ws: hn bf16 (40,894,464) | cn bf16 (3,145,728) | S_all (8,192) | alignedD (106,496)
  char* ws = (char*)d_ws;
  unsigned short* hn = (unsigned short*)ws;
  unsigned short* cn = (unsigned short*)(ws + (size_t)NROW * H_ * 2);
  float* S_all    = (float*)(ws + (size_t)NROW * H_ * 2 + (size_t)B_ * H_ * 2);
  float* alignedD = (float*)(ws + (size_t)NROW * H_ * 2 + (size_t)B_ * H_ * 2 + B_ * sizeof(float));

  hipMemsetAsync(S_all, 0, B_ * sizeof(float), stream);
  hipMemsetAsync(out, 0, sizeof(float), stream);

  k_normalize<<<(B_ + NROW) / 4, 256, 0, stream>>>(cls, hidden, cn, hn);
  k_gemm<<<8 * 104, 512, 0, stream>>>(cn, hn, S_all, alignedD);
  k_finalize<<<B_ / 256, 256, 0, stream>>>(S_all, alignedD, out);
}

// Round 5
// 179.832 us; speedup vs baseline: 4.3381x; 4.3381x over previous
//
#include <hip/hip_runtime.h>
#include <cstdint>
#include <cstddef>

#define B_    2048
#define L_    13
#define H_    768
#define NROW  (B_ * L_)          // 26624 flattened hidden rows
#define RTEMP 20.0f              // 1 / 0.05
#define NT    24                 // K tiles: 768 / 32
#define RS    1536               // global row stride bytes (H_ * 2)

typedef short bf16x8 __attribute__((ext_vector_type(8)));
typedef float f32x4  __attribute__((ext_vector_type(4)));

static __device__ __forceinline__ unsigned short f2bf(float f) {
  union { float f; unsigned int i; } v; v.f = f;
  unsigned int r = v.i + 0x7fffu + ((v.i >> 16) & 1u);   // RNE
  return (unsigned short)(r >> 16);
}
static __device__ __forceinline__ unsigned int pack2(float a, float b) {
  return ((unsigned int)f2bf(b) << 16) | (unsigned int)f2bf(a);
}

__device__ __forceinline__ void llds16(const void* g, void* l) {
  __builtin_amdgcn_global_load_lds(
      (const __attribute__((address_space(1))) void*)g,
      (__attribute__((address_space(3))) void*)l, 16, 0, 0);
}

#define BAR do { asm volatile("" ::: "memory");            \
    __builtin_amdgcn_s_barrier();                          \
    asm volatile("" ::: "memory"); } while (0)
#define WAIT_LGKM do { asm volatile("s_waitcnt lgkmcnt(0)" ::: "memory"); \
    __builtin_amdgcn_sched_barrier(0); } while (0)

// ---------------------------------------------------------------------------
// Kernel 1: L2-normalize rows, cast to bf16. One wave per row, 4 rows/block.
// ---------------------------------------------------------------------------
__global__ __launch_bounds__(256) void k_normalize(
    const float* __restrict__ cls, const float* __restrict__ hidden,
    unsigned short* __restrict__ cn, unsigned short* __restrict__ hn)
{
  const int wid = threadIdx.x >> 6, lane = threadIdx.x & 63;
  const int row = blockIdx.x * 4 + wid;
  const float4* src; unsigned short* dst;
  if (row < B_) { src = (const float4*)(cls + (size_t)row * H_);          dst = cn + (size_t)row * H_; }
  else          { src = (const float4*)(hidden + (size_t)(row - B_) * H_); dst = hn + (size_t)(row - B_) * H_; }

  float4 x0 = src[lane], x1 = src[lane + 64], x2 = src[lane + 128];
  float ss = x0.x*x0.x + x0.y*x0.y + x0.z*x0.z + x0.w*x0.w
           + x1.x*x1.x + x1.y*x1.y + x1.z*x1.z + x1.w*x1.w
           + x2.x*x2.x + x2.y*x2.y + x2.z*x2.z + x2.w*x2.w;
#pragma unroll
  for (int m = 1; m < 64; m <<= 1) ss += __shfl_xor(ss, m);
  const float sc = 1.0f / fmaxf(sqrtf(ss), 1e-8f);

  uint2* d2 = (uint2*)dst;
  uint2 p;
  p.x = pack2(x0.x * sc, x0.y * sc); p.y = pack2(x0.z * sc, x0.w * sc); d2[lane]       = p;
  p.x = pack2(x1.x * sc, x1.y * sc); p.y = pack2(x1.z * sc, x1.w * sc); d2[lane + 64]  = p;
  p.x = pack2(x2.x * sc, x2.y * sc); p.y = pack2(x2.z * sc, x2.w * sc); d2[lane + 128] = p;
}

// ---------------------------------------------------------------------------
// Kernel 2: 256x256 tile, BK=32, 8 waves (2M x 4N), wave tile 128x64
// (62%-MfmaUtil LDS-BW-cap geometry). 2-slot LDS double-buffer (2 x 32KB =
// 64KB -> 2 blocks/CU from the LDS limit), ONE barrier per K-tile, stage
// issued at tile top (distance-1; loads get the ds_read+MFMA span to land,
// B-panels L2-hot via per-XCD M-inner mapping). Paired-row XOR swizzle
// (R2/R3-validated, 0 conflicts). Fused exp/mask/row-sum epilogue.
// NOTE: min-waves hint is 2 (256 unified regs/wave). R4's (512,4) capped at
// 128 regs -> accumulator spilled to scratch -> 2 GB of spill traffic.
// ---------------------------------------------------------------------------
__global__ __launch_bounds__(512, 2) void k_gemm(
    const unsigned short* __restrict__ cn,
    const unsigned short* __restrict__ hn,
    float* __restrict__ S_all,
    float* __restrict__ alignedD)
{
  __shared__ __align__(16) char lds[65536];   // 2 slots x (A 16KB | B 16KB)

  const int tid  = threadIdx.x;
  const int lane = tid & 63;
  const int wid  = tid >> 6;           // 0..7
  const int wm   = wid >> 2;           // 0..1  (M half: 128 rows)
  const int wn   = wid & 3;            // 0..3  (N quarter: 64 cols)
  const int fr   = lane & 15, q = lane >> 4, fr2 = (lane & 15) >> 1;

  // 832 blocks = 8 XCD x (13 N-panels x 8 M-panels), M-inner: B-panel
  // (393KB) L2-hot across its 8 M-blocks; cn (3.1MB) L2-resident per XCD.
  const int wg   = blockIdx.x;
  const int idx  = wg >> 3;
  const int brow = (idx & 7) * 256;
  const int bcol = ((wg & 7) * 13 + (idx >> 3)) * 256;

  // --- staging map (linear LDS dest, inverse-swizzled global source) ------
  const int slot_un = (tid & 7) ^ ((tid >> 3) & 7);
  const int srow = 2 * (tid >> 3) + (slot_un >> 2);   // 0..127
  const int scb  = (slot_un & 3) << 4;
  const char* gA = (const char*)cn + (size_t)(brow + srow) * RS + scb;
  const char* gB = (const char*)hn + (size_t)(bcol + srow) * RS + scb;
  char* ldst = lds + tid * 16;

#define STAGE_A(slot, t) do { char* d_ = ldst + (slot) * 32768;           \
    llds16(gA + (t) * 64,            d_);                                 \
    llds16(gA + (t) * 64 + 128 * RS, d_ + 8192); } while (0)
#define STAGE_B(slot, t) do { char* d_ = ldst + (slot) * 32768 + 16384;   \
    llds16(gB + (t) * 64,            d_);                                 \
    llds16(gB + (t) * 64 + 128 * RS, d_ + 8192); } while (0)

  // --- fragment read offsets (paired-row XOR swizzle) ---------------------
  const int swz  = ((((fr & 1) << 2) | q) ^ (fr2 & 7)) << 4;
  const int offA = (wm * 64 + fr2) * 128 + swz;            // + m*1024
  const int offB = 16384 + (wn * 32 + fr2) * 128 + swz;    // + n*1024

  f32x4 acc[8][4] = {};

  // prologue: K-tile 0 staged
  STAGE_A(0, 0); STAGE_B(0, 0);
  asm volatile("s_waitcnt vmcnt(0)" ::: "memory");
  BAR;

  for (int t = 0; t < NT; ++t) {
    const char* bb = lds + (t & 1) * 32768;

    // stage next tile FIRST (max issue->wait gap; WAR safe: slot (t+1)&1
    // was last read in tile t-1, completed behind the barrier)
    if (t + 1 < NT) { STAGE_A((t + 1) & 1, t + 1); STAGE_B((t + 1) & 1, t + 1); }

    bf16x8 a0[4], a1[4], bf[4];
#pragma unroll
    for (int i = 0; i < 4; ++i) a0[i] = *(const bf16x8*)(bb + offA + i * 1024);
#pragma unroll
    for (int i = 0; i < 4; ++i) a1[i] = *(const bf16x8*)(bb + offA + 4096 + i * 1024);
#pragma unroll
    for (int i = 0; i < 4; ++i) bf[i] = *(const bf16x8*)(bb + offB + i * 1024);
    WAIT_LGKM;

    __builtin_amdgcn_s_setprio(1);
#pragma unroll
    for (int mi = 0; mi < 4; ++mi)
#pragma unroll
      for (int ni = 0; ni < 4; ++ni)
        acc[mi][ni] = __builtin_amdgcn_mfma_f32_16x16x32_bf16(
            a0[mi], bf[ni], acc[mi][ni], 0, 0, 0);
#pragma unroll
    for (int mi = 0; mi < 4; ++mi)
#pragma unroll
      for (int ni = 0; ni < 4; ++ni)
        acc[mi + 4][ni] = __builtin_amdgcn_mfma_f32_16x16x32_bf16(
            a1[mi], bf[ni], acc[mi + 4][ni], 0, 0, 0);
    __builtin_amdgcn_s_setprio(0);

    // only the next tile's 4 loads are in flight here; they've had the
    // whole ds_read+MFMA span to land -> near-free wait
    asm volatile("s_waitcnt vmcnt(0)" ::: "memory");
    BAR;
  }
#undef STAGE_A
#undef STAGE_B

  // --- epilogue: row = brow+wm*128+m*16+q*4+j, col = bcol+wn*64+n*16+fr ---
  const int rowb = brow + wm * 128;
  const int colb = bcol + wn * 64;
#pragma unroll
  for (int mi = 0; mi < 8; ++mi) {
#pragma unroll
    for (int j = 0; j < 4; ++j) {
      const int grow = rowb + mi * 16 + q * 4 + j;
      float v = 0.f;
#pragma unroll
      for (int ni = 0; ni < 4; ++ni) {
        const int gcol = colb + ni * 16 + fr;
        const float a = acc[mi][ni][j];
        if ((unsigned)(gcol - grow * 13) < 13u) alignedD[gcol] = a;  // raw dot
        v += ((gcol & 2047) == grow) ? 0.f : __expf(RTEMP * a);     // masked sum
      }
      v += __shfl_xor(v, 1); v += __shfl_xor(v, 2);
      v += __shfl_xor(v, 4); v += __shfl_xor(v, 8);
      if (fr == 0) atomicAdd(&S_all[grow], v);
    }
  }
}

// ---------------------------------------------------------------------------
// Kernel 3: per row i: loss_i = sum_l [ log(exp(20 d_l) + s_i) - 20 d_l ].
// ---------------------------------------------------------------------------
__global__ __launch_bounds__(256) void k_finalize(
    const float* __restrict__ S_all, const float* __restrict__ alignedD,
    float* __restrict__ out)
{
  const int i = blockIdx.x * 256 + threadIdx.x;
  const int lane = threadIdx.x & 63, wid = threadIdx.x >> 6;
  const float s = S_all[i];
  float accv = 0.f;
#pragma unroll
  for (int l = 0; l < L_; l++) {
    const float d = RTEMP * alignedD[i * L_ + l];
    accv += logf(__expf(d) + s) - d;
  }
#pragma unroll
  for (int m = 1; m < 64; m <<= 1) accv += __shfl_xor(accv, m);
  __shared__ float wsum[4];
  if (lane == 0) wsum[wid] = accv;
  __syncthreads();
  if (threadIdx.x == 0)
    atomicAdd(out, (wsum[0] + wsum[1] + wsum[2] + wsum[3]) * (1.0f / (float)(B_ * L_)));
}

// ---------------------------------------------------------------------------
extern "C" void kernel_launch(void* const* d_in, const int* in_sizes, int n_in,
                              void* d_out, int out_size, void* d_ws, size_t ws_size,
                              hipStream_t stream) {
  const float* cls    = (const float*)d_in[0];
  const float* hidden = (const float*)d_in[1];
  float* out = (float*)d_out;

  // ws: hn bf16 (40,894,464) | cn bf16 (3,145,728) | S_all (8,192) | alignedD (106,496)
  char* ws = (char*)d_ws;
  unsigned short* hn = (unsigned short*)ws;
  unsigned short* cn = (unsigned short*)(ws + (size_t)NROW * H_ * 2);
  float* S_all    = (float*)(ws + (size_t)NROW * H_ * 2 + (size_t)B_ * H_ * 2);
  float* alignedD = (float*)(ws + (size_t)NROW * H_ * 2 + (size_t)B_ * H_ * 2 + B_ * sizeof(float));

  hipMemsetAsync(S_all, 0, B_ * sizeof(float), stream);
  hipMemsetAsync(out, 0, sizeof(float), stream);

  k_normalize<<<(B_ + NROW) / 4, 256, 0, stream>>>(cls, hidden, cn, hn);
  k_gemm<<<8 * 104, 512, 0, stream>>>(cn, hn, S_all, alignedD);
  k_finalize<<<B_ / 256, 256, 0, stream>>>(S_all, alignedD, out);
}

// Round 6
// 147.580 us; speedup vs baseline: 5.2862x; 1.2185x over previous
//
#include <hip/hip_runtime.h>
#include <cstdint>
#include <cstddef>

#define B_    2048
#define L_    13
#define H_    768
#define NROW  (B_ * L_)          // 26624 flattened hidden rows
#define RTEMP 20.0f              // 1 / 0.05
#define NT    24                 // K tiles: 768 / 32
#define RS    1536               // global row stride bytes (H_ * 2)
#define SLOT  24576              // LDS slot: A 16KB + B 8KB
#define NSLOT 3

typedef short bf16x8 __attribute__((ext_vector_type(8)));
typedef float f32x4  __attribute__((ext_vector_type(4)));

static __device__ __forceinline__ unsigned short f2bf(float f) {
  union { float f; unsigned int i; } v; v.f = f;
  unsigned int r = v.i + 0x7fffu + ((v.i >> 16) & 1u);   // RNE
  return (unsigned short)(r >> 16);
}
static __device__ __forceinline__ unsigned int pack2(float a, float b) {
  return ((unsigned int)f2bf(b) << 16) | (unsigned int)f2bf(a);
}

__device__ __forceinline__ void llds16(const void* g, void* l) {
  __builtin_amdgcn_global_load_lds(
      (const __attribute__((address_space(1))) void*)g,
      (__attribute__((address_space(3))) void*)l, 16, 0, 0);
}

#define BAR do { asm volatile("" ::: "memory");            \
    __builtin_amdgcn_s_barrier();                          \
    asm volatile("" ::: "memory"); } while (0)

// ---------------------------------------------------------------------------
// Kernel 1: L2-normalize rows, cast to bf16. One wave per row, 4 rows/block.
// ---------------------------------------------------------------------------
__global__ __launch_bounds__(256) void k_normalize(
    const float* __restrict__ cls, const float* __restrict__ hidden,
    unsigned short* __restrict__ cn, unsigned short* __restrict__ hn)
{
  const int wid = threadIdx.x >> 6, lane = threadIdx.x & 63;
  const int row = blockIdx.x * 4 + wid;
  const float4* src; unsigned short* dst;
  if (row < B_) { src = (const float4*)(cls + (size_t)row * H_);          dst = cn + (size_t)row * H_; }
  else          { src = (const float4*)(hidden + (size_t)(row - B_) * H_); dst = hn + (size_t)(row - B_) * H_; }

  float4 x0 = src[lane], x1 = src[lane + 64], x2 = src[lane + 128];
  float ss = x0.x*x0.x + x0.y*x0.y + x0.z*x0.z + x0.w*x0.w
           + x1.x*x1.x + x1.y*x1.y + x1.z*x1.z + x1.w*x1.w
           + x2.x*x2.x + x2.y*x2.y + x2.z*x2.z + x2.w*x2.w;
#pragma unroll
  for (int m = 1; m < 64; m <<= 1) ss += __shfl_xor(ss, m);
  const float sc = 1.0f / fmaxf(sqrtf(ss), 1e-8f);

  uint2* d2 = (uint2*)dst;
  uint2 p;
  p.x = pack2(x0.x * sc, x0.y * sc); p.y = pack2(x0.z * sc, x0.w * sc); d2[lane]       = p;
  p.x = pack2(x1.x * sc, x1.y * sc); p.y = pack2(x1.z * sc, x1.w * sc); d2[lane + 64]  = p;
  p.x = pack2(x2.x * sc, x2.y * sc); p.y = pack2(x2.z * sc, x2.w * sc); d2[lane + 128] = p;
}

// ---------------------------------------------------------------------------
// Kernel 2: BM=256 x BN=128 tile, BK=32, 4 waves (2M x 2N), wave tile 128x64
// (low-LDS-traffic geometry, MFMA-bound cap ~52%). 256-thread blocks so the
// ~224-reg waves (128 AGPR acc + ~96 VGPR) give 2 blocks/CU -> de-phased
// inter-block overlap + no lockstep tail (1664 staggered blocks).
// 3-slot LDS ring (72KB), stage t+2 at step top, counted vmcnt(6)+barrier at
// step END (t+1 guaranteed landed for all waves; in-flight ~2 steps).
// Paired-row XOR swizzle (R2-validated, 0 conflicts). Fused epilogue.
// ---------------------------------------------------------------------------
__global__ __launch_bounds__(256, 2) void k_gemm(
    const unsigned short* __restrict__ cn,
    const unsigned short* __restrict__ hn,
    float* __restrict__ S_all,
    float* __restrict__ alignedD)
{
  __shared__ __align__(16) char lds[NSLOT * SLOT];

  const int tid  = threadIdx.x;
  const int lane = tid & 63;
  const int wid  = tid >> 6;           // 0..3
  const int wm   = wid >> 1;           // 0..1  (M half: 128 rows)
  const int wn   = wid & 1;            // 0..1  (N half: 64 cols)
  const int fr   = lane & 15, q = lane >> 4, fr2 = (lane & 15) >> 1;

  // 1664 blocks = 8 XCD x (26 N-chunks x 8 M-panels), M-inner: B-panel
  // (197KB) L2-hot across 8 M-blocks; cn (3.1MB) L2-resident per XCD.
  const int wg   = blockIdx.x;
  const int xcd  = wg & 7;
  const int idx  = wg >> 3;            // 0..207
  const int brow = (idx & 7) * 256;
  const int bcol = (xcd * 26 + (idx >> 3)) * 128;

  // --- staging map (linear LDS dest, inverse-swizzled global source) ------
  const int slot_un = (tid & 7) ^ ((tid >> 3) & 7);
  const int srow = 2 * (tid >> 3) + (slot_un >> 2);   // 0..63
  const int scb  = (slot_un & 3) << 4;
  const char* gA = (const char*)cn + (size_t)(brow + srow) * RS + scb;
  const char* gB = (const char*)hn + (size_t)(bcol + srow) * RS + scb;
  char* ldst = lds + tid * 16;

  // A slot: rows 0..255 as 4 x 4KB ; B slot (+16384): rows 0..127 as 2 x 4KB
#define STAGE(sbase, t) do {                                  \
    char* d_ = ldst + (sbase);                                \
    const char* a_ = gA + (t) * 64;                           \
    llds16(a_,            d_);                                \
    llds16(a_ +  64 * RS, d_ + 4096);                         \
    llds16(a_ + 128 * RS, d_ + 8192);                         \
    llds16(a_ + 192 * RS, d_ + 12288);                        \
    const char* b_ = gB + (t) * 64;                           \
    llds16(b_,            d_ + 16384);                        \
    llds16(b_ +  64 * RS, d_ + 20480);                        \
  } while (0)

  // --- fragment read offsets (paired-row XOR swizzle) ---------------------
  const int swz  = ((((fr & 1) << 2) | q) ^ (fr2 & 7)) << 4;
  const int offA = wm * 8192 + fr2 * 128 + swz;             // + m*1024, m<8
  const int offB = 16384 + wn * 4096 + fr2 * 128 + swz;     // + n*1024, n<4

  f32x4 acc[8][4] = {};

  // prologue: steps 0,1 staged (12 loads); vmcnt(6) -> step 0 landed
  STAGE(0, 0);
  STAGE(SLOT, 1);
  asm volatile("s_waitcnt vmcnt(6)" ::: "memory");
  BAR;

  int baseR = 0, baseS = 2 * SLOT;
  for (int t = 0; t < NT; ++t) {
    // stage step t+2 (slot = (t+2)%3; WAR-safe: that slot's reads finished
    // in step t-1, behind the barrier we just crossed)
    if (t + 2 < NT) STAGE(baseS, t + 2);

    const char* bb = lds + baseR;
    bf16x8 af[8], bf[4];
#pragma unroll
    for (int i = 0; i < 8; ++i) af[i] = *(const bf16x8*)(bb + offA + i * 1024);
#pragma unroll
    for (int i = 0; i < 4; ++i) bf[i] = *(const bf16x8*)(bb + offB + i * 1024);

    __builtin_amdgcn_s_setprio(1);
#pragma unroll
    for (int mi = 0; mi < 8; ++mi)
#pragma unroll
      for (int ni = 0; ni < 4; ++ni)
        acc[mi][ni] = __builtin_amdgcn_mfma_f32_16x16x32_bf16(
            af[mi], bf[ni], acc[mi][ni], 0, 0, 0);
    __builtin_amdgcn_s_setprio(0);

    // end-of-step guarantee: step t+1's 6 loads landed (t+2's may fly on)
    if (t + 2 < NT)      { asm volatile("s_waitcnt vmcnt(6)" ::: "memory"); BAR; }
    else if (t + 1 < NT) { asm volatile("s_waitcnt vmcnt(0)" ::: "memory"); BAR; }

    baseR += SLOT; if (baseR >= NSLOT * SLOT) baseR = 0;
    baseS += SLOT; if (baseS >= NSLOT * SLOT) baseS = 0;
  }
#undef STAGE

  // --- epilogue: row = brow+wm*128+m*16+q*4+j, col = bcol+wn*64+n*16+fr ---
  const int rowb = brow + wm * 128;
  const int colb = bcol + wn * 64;
#pragma unroll
  for (int mi = 0; mi < 8; ++mi) {
#pragma unroll
    for (int j = 0; j < 4; ++j) {
      const int grow = rowb + mi * 16 + q * 4 + j;
      float v = 0.f;
#pragma unroll
      for (int ni = 0; ni < 4; ++ni) {
        const int gcol = colb + ni * 16 + fr;
        const float a = acc[mi][ni][j];
        if ((unsigned)(gcol - grow * 13) < 13u) alignedD[gcol] = a;  // raw dot
        v += ((gcol & 2047) == grow) ? 0.f : __expf(RTEMP * a);     // masked sum
      }
      v += __shfl_xor(v, 1); v += __shfl_xor(v, 2);
      v += __shfl_xor(v, 4); v += __shfl_xor(v, 8);
      if (fr == 0) atomicAdd(&S_all[grow], v);
    }
  }
}

// ---------------------------------------------------------------------------
// Kernel 3: per row i: loss_i = sum_l [ log(exp(20 d_l) + s_i) - 20 d_l ].
// ---------------------------------------------------------------------------
__global__ __launch_bounds__(256) void k_finalize(
    const float* __restrict__ S_all, const float* __restrict__ alignedD,
    float* __restrict__ out)
{
  const int i = blockIdx.x * 256 + threadIdx.x;
  const int lane = threadIdx.x & 63, wid = threadIdx.x >> 6;
  const float s = S_all[i];
  float accv = 0.f;
#pragma unroll
  for (int l = 0; l < L_; l++) {
    const float d = RTEMP * alignedD[i * L_ + l];
    accv += logf(__expf(d) + s) - d;
  }
#pragma unroll
  for (int m = 1; m < 64; m <<= 1) accv += __shfl_xor(accv, m);
  __shared__ float wsum[4];
  if (lane == 0) wsum[wid] = accv;
  __syncthreads();
  if (threadIdx.x == 0)
    atomicAdd(out, (wsum[0] + wsum[1] + wsum[2] + wsum[3]) * (1.0f / (float)(B_ * L_)));
}

// ---------------------------------------------------------------------------
extern "C" void kernel_launch(void* const* d_in, const int* in_sizes, int n_in,
                              void* d_out, int out_size, void* d_ws, size_t ws_size,
                              hipStream_t stream) {
  const float* cls    = (const float*)d_in[0];
  const float* hidden = (const float*)d_in[1];
  float* out = (float*)d_out;

  // ws: hn bf16 (40,894,464) | cn bf16 (3,145,728) | S_all (8,192) | alignedD (106,496)
  char* ws = (char*)d_ws;
  unsigned short* hn = (unsigned short*)ws;
  unsigned short* cn = (unsigned short*)(ws + (size_t)NROW * H_ * 2);
  float* S_all    = (float*)(ws + (size_t)NROW * H_ * 2 + (size_t)B_ * H_ * 2);
  float* alignedD = (float*)(ws + (size_t)NROW * H_ * 2 + (size_t)B_ * H_ * 2 + B_ * sizeof(float));

  hipMemsetAsync(S_all, 0, B_ * sizeof(float), stream);
  hipMemsetAsync(out, 0, sizeof(float), stream);

  k_normalize<<<(B_ + NROW) / 4, 256, 0, stream>>>(cls, hidden, cn, hn);
  k_gemm<<<8 * 208, 256, 0, stream>>>(cn, hn, S_all, alignedD);
  k_finalize<<<B_ / 256, 256, 0, stream>>>(S_all, alignedD, out);
}